// Round 2
// baseline (94.621 us; speedup 1.0000x reference)
//
#include <hip/hip_runtime.h>

#define D 64
#define NN 10

typedef __bf16 bf16x8 __attribute__((ext_vector_type(8)));
typedef float f32x4 __attribute__((ext_vector_type(4)));

// ---------------------------------------------------------------------------
// d_ws layout:  [0, 8192)    __bf16 Apack[4096]  — M in MFMA A-fragment order
//               [8192, 8448) float  cvec[64]     — collapsed bias
//
// Apack order: for fragment (kc in 0..1, nc in 0..3), lane in 0..63, j in 0..7:
//   Apack[((kc*4+nc)*64 + lane)*8 + j] = bf16( M[kc*32 + (lane>>4)*8 + j][nc*16 + (lane&15)] )
// so apply does one dwordx4 load per fragment (perfectly coalesced).
// ---------------------------------------------------------------------------

// Kernel 1: collapse the linear DAG.  Block r<64: row r of M (M_0 = I).
// Block 64: bias row (c_0 = 0, picks up b[f,t]).
// k-split across 4 waves (all waves busy at every t); fully unrolled t,f so the
// scheduler issues all of a t-step's loads before its FMAs; 1 barrier per t.
__global__ __launch_bounds__(256) void wired_build(const float* __restrict__ W,
                                                   const float* __restrict__ Bv,
                                                   __bf16* __restrict__ Apack,
                                                   float* __restrict__ cvec) {
  __shared__ float hist[NN][D];
  __shared__ float part[2][4][D];
  const int r = blockIdx.x;            // 0..63 = M rows, 64 = bias row
  const int lane = threadIdx.x & 63;
  const int w = threadIdx.x >> 6;      // wave 0..3 owns k-slice [w*16, w*16+16)

  // Every wave writes the full row (identical values) -> own-wave reads are
  // ordered by LDS in-order semantics; no barrier needed between iterations
  // beyond the one guarding the cross-wave partials.
  hist[0][lane] = (r < D && lane == r) ? 1.0f : 0.0f;
  __syncthreads();

#pragma unroll
  for (int t = 1; t < NN; ++t) {
    float a0 = 0.f, a1 = 0.f, a2 = 0.f, a3 = 0.f;
#pragma unroll
    for (int f = 0; f < t; ++f) {
      const float* wft = W + (size_t)(f * NN + t) * D * D + w * 16 * D + lane;
      const float* hf = &hist[f][w * 16];
#pragma unroll
      for (int kk = 0; kk < 16; kk += 4) {
        a0 += hf[kk + 0] * wft[(kk + 0) * D];   // coalesced 256B/wave, LDS broadcast
        a1 += hf[kk + 1] * wft[(kk + 1) * D];
        a2 += hf[kk + 2] * wft[(kk + 2) * D];
        a3 += hf[kk + 3] * wft[(kk + 3) * D];
      }
      if (r == D && w == 0) a0 += Bv[(f * NN + t) * D + lane];  // bias row
    }
    part[t & 1][w][lane] = (a0 + a1) + (a2 + a3);
    __syncthreads();                   // the only barrier per t
    float s = part[t & 1][0][lane] + part[t & 1][1][lane] +
              part[t & 1][2][lane] + part[t & 1][3][lane];
    hist[t][lane] = s;                 // redundant identical write by all waves
  }

  if (threadIdx.x < D) {
    float v = hist[NN - 1][threadIdx.x];
    if (r < D) {
      // scatter row r into A-fragment order (k = r)
      const int kc = r >> 5, q = (r >> 3) & 3, j = r & 7;
      const int nc = threadIdx.x >> 4, l15 = threadIdx.x & 15;
      Apack[(size_t)(((kc * 4 + nc) * 64) + q * 16 + l15) * 8 + j] = (__bf16)v;
    } else {
      cvec[threadIdx.x] = v;
    }
  }
}

// Kernel 2: out = x @ M + c, transposed MFMA so stores are dwordx4.
// D[m][n] = sum_k A[m][k]*B[k][n] with A = M^T chunk (register-resident,
// pre-packed), B = x^T tile.  D row = output col within 16-chunk, D col =
// batch row -> lane holds 4 CONSECUTIVE output floats -> float4 store.
// Bias folded into acc init.  1 tile (16 batch rows) per wave, no loop.
__global__ __launch_bounds__(256) void wired_apply(const float* __restrict__ x,
                                                   const __bf16* __restrict__ Apack,
                                                   const float* __restrict__ cvec,
                                                   float* __restrict__ out,
                                                   int ntiles) {
  const int lane = threadIdx.x & 63;
  const int wave = threadIdx.x >> 6;
  const int l15 = lane & 15;
  const int quad = lane >> 4;

  // 8 coalesced 16B loads: the whole M as A-fragments, resident in VGPRs.
  bf16x8 afrag[2][4];
#pragma unroll
  for (int kc = 0; kc < 2; ++kc)
#pragma unroll
    for (int nc = 0; nc < 4; ++nc)
      afrag[kc][nc] = *(const bf16x8*)(Apack + (size_t)(((kc * 4 + nc) * 64) + lane) * 8);

  float4 cq[4];
#pragma unroll
  for (int nc = 0; nc < 4; ++nc)
    cq[nc] = *(const float4*)(cvec + nc * 16 + quad * 4);

  const int tile = blockIdx.x * 4 + wave;
  if (tile >= ntiles) return;

  // B fragment = x^T: lane reads 8 contiguous floats of batch row l15, twice.
  const float* xr = x + (size_t)(tile * 16 + l15) * D + quad * 8;
  float4 v0 = *(const float4*)(xr);
  float4 v1 = *(const float4*)(xr + 4);
  float4 v2 = *(const float4*)(xr + 32);
  float4 v3 = *(const float4*)(xr + 36);
  bf16x8 bf0, bf1;
  bf0[0] = (__bf16)v0.x; bf0[1] = (__bf16)v0.y; bf0[2] = (__bf16)v0.z; bf0[3] = (__bf16)v0.w;
  bf0[4] = (__bf16)v1.x; bf0[5] = (__bf16)v1.y; bf0[6] = (__bf16)v1.z; bf0[7] = (__bf16)v1.w;
  bf1[0] = (__bf16)v2.x; bf1[1] = (__bf16)v2.y; bf1[2] = (__bf16)v2.z; bf1[3] = (__bf16)v2.w;
  bf1[4] = (__bf16)v3.x; bf1[5] = (__bf16)v3.y; bf1[6] = (__bf16)v3.z; bf1[7] = (__bf16)v3.w;

  float* orow = out + (size_t)(tile * 16 + l15) * D + quad * 4;
#pragma unroll
  for (int nc = 0; nc < 4; ++nc) {
    f32x4 acc = {cq[nc].x, cq[nc].y, cq[nc].z, cq[nc].w};  // bias as acc init
    acc = __builtin_amdgcn_mfma_f32_16x16x32_bf16(afrag[0][nc], bf0, acc, 0, 0, 0);
    acc = __builtin_amdgcn_mfma_f32_16x16x32_bf16(afrag[1][nc], bf1, acc, 0, 0, 0);
    *(float4*)(orow + nc * 16) = {acc[0], acc[1], acc[2], acc[3]};  // dwordx4 store
  }
}

extern "C" void kernel_launch(void* const* d_in, const int* in_sizes, int n_in,
                              void* d_out, int out_size, void* d_ws, size_t ws_size,
                              hipStream_t stream) {
  const float* x = (const float*)d_in[0];   // [B, 64] fp32
  const float* W = (const float*)d_in[1];   // [10,10,64,64] fp32
  const float* Bv = (const float*)d_in[2];  // [10,10,64] fp32
  float* out = (float*)d_out;               // [B, 64] fp32

  __bf16* Apack = (__bf16*)d_ws;
  float* cvec = (float*)((char*)d_ws + 8192);

  const int nrows = in_sizes[0] / D;        // 65536
  const int ntiles = nrows / 16;            // 4096
  const int nblocks = (ntiles + 3) / 4;     // 1024 -> 1 tile per wave

  wired_build<<<65, 256, 0, stream>>>(W, Bv, Apack, cvec);
  wired_apply<<<nblocks, 256, 0, stream>>>(x, Apack, cvec, out, ntiles);
}